// Round 11
// baseline (210.103 us; speedup 1.0000x reference)
//
#include <hip/hip_runtime.h>

// Fastformer additive attention, MI355X (round 18 -- MEASUREMENT PROBE):
//   - Base: r14 VERBATIM (163.2us best). r17's tri-buffer (+3.0) reverted.
//   - Probe: stage1 and stage2 are each launched TWICE (idempotent: pure
//     functions of unchanged inputs). dur_us - 163.2 - ~2us(gaps) = s1+s2,
//     splitting the kernel budget {stages} vs {gemms+conv+gaps} decisively.
//   - Next round reverts to the 6-launch pipeline and acts on the split.
// Pipeline: conv -> QK -> s1 -> s1 -> s2 -> s2 -> VU -> OUT  (8 launches)

#define SCL2 0.1803368801f   /* 0.125 * log2(e) */
typedef unsigned short u16;
typedef __attribute__((ext_vector_type(8))) short short8;   // 8 bf16 = 4 VGPR
typedef __attribute__((ext_vector_type(4))) float f32x4;

#define MFMA16(a, b, c) __builtin_amdgcn_mfma_f32_16x16x32_bf16((a), (b), (c), 0, 0, 0)

__device__ __forceinline__ float bf2f(u16 u) {
    union { unsigned int i; float f; } v; v.i = ((unsigned int)u) << 16; return v.f;
}
__device__ __forceinline__ u16 f2bf(float f) {
    union { float f; unsigned int i; } v; v.f = f;
    unsigned int x = v.i;
    return (u16)((x + 0x7FFFu + ((x >> 16) & 1u)) >> 16);
}

// async global->LDS, 16B per lane; LDS dest = wave-uniform base + lane*16
__device__ __forceinline__ void gload16(const u16* g, u16* l) {
    __builtin_amdgcn_global_load_lds(
        (__attribute__((address_space(1))) void*)(void*)g,
        (__attribute__((address_space(3))) void*)l, 16, 0, 0);
}

// ---------------------------------------------------------------------------
// f32 -> bf16: w_qkv | w_out | wq | wk | x   (contiguous ws block)
// ---------------------------------------------------------------------------
__global__ __launch_bounds__(256) void conv_kernel(
    const float* __restrict__ w_qkv, const float* __restrict__ w_out,
    const float* __restrict__ wq, const float* __restrict__ wk,
    const float* __restrict__ x, u16* __restrict__ wsb)
{
    const int idx = (blockIdx.x * 256 + threadIdx.x) * 4;
    const float* src; int off;
    if      (idx < 786432)  { src = w_qkv; off = idx; }
    else if (idx < 1048576) { src = w_out; off = idx - 786432; }
    else if (idx < 1114112) { src = wq;    off = idx - 1048576; }
    else if (idx < 1179648) { src = wk;    off = idx - 1114112; }
    else                    { src = x;     off = idx - 1179648; }
    float4 v = *(const float4*)(src + off);
    ushort4 o; o.x = f2bf(v.x); o.y = f2bf(v.y); o.z = f2bf(v.z); o.w = f2bf(v.w);
    *(ushort4*)(wsb + idx) = o;
}

// ---------------------------------------------------------------------------
// MFMA GEMM (round-9 verbatim): tile 128M x (NCT*16)N, BK=64, K=512, 4 waves.
// Double-buffered gload_lds staging (linear LDS dest, source chunk swizzled
// with (lane&7)^(lane>>3)); fragment reads XOR chunk idx with (row&7).
// K-loop: stage(next buf) -> sched_barrier -> compute(cur) -> syncthreads.
// Final compute reads buf0; C bounce (padded stride) overlays buf1.
// ---------------------------------------------------------------------------
#define MQK 0
#define MVU 1
#define MOUT 2

template <int MODE, int NCT>
__global__ __launch_bounds__(256) void gemm_k(
    const u16* __restrict__ Ab, int lda, int acol,
    const u16* __restrict__ Wb, const float* __restrict__ bias,
    const float* __restrict__ kg, const u16* __restrict__ qkws_ro,
    u16* __restrict__ qkws, float* __restrict__ outp,
    float* __restrict__ qsout, float* __restrict__ ksout)
{
    constexpr int BN = NCT * 16;            // tile N
    constexpr int CST = BN + 8;             // padded bounce stride (u16)
    constexpr int ASZ = 128 * 64;           // A elems per buffer
    constexpr int BSZ = BN * 64;            // B elems per buffer
    constexpr int HALF = ASZ + BSZ;         // one double-buffer half
    constexpr int CELEM = 128 * CST;
    constexpr int SMSZ = (2 * HALF > HALF + CELEM) ? 2 * HALF : HALF + CELEM;
    __shared__ u16 sm[SMSZ];
    u16* const Cb = sm + HALF;              // C bounce overlays buf1 only

    const int t = threadIdx.x;
    const int w = t >> 6, lane = t & 63, s = lane & 15, quad = lane >> 4;
    const int sx = lane & 7;                // row&7 of every fragment row read

    // T1: bijective XCD swizzle (nwg % 8 == 0)
    const int nwgy = gridDim.y;
    const int nwg = gridDim.x * nwgy;
    const int flat = blockIdx.y * gridDim.x + blockIdx.x;
    const int swz = (flat & 7) * (nwg >> 3) + (flat >> 3);
    const int by = swz % nwgy, bx = swz / nwgy;
    const int bm = bx * 128, jn0 = by * BN;

    const int r8 = lane >> 3;                       // staged row within 8-row group
    const int c8x = ((lane & 7) ^ r8) << 3;         // swizzled source chunk (u16)

    f32x4 acc[2][NCT];
#pragma unroll
    for (int i = 0; i < 2; ++i)
#pragma unroll
        for (int j = 0; j < NCT; ++j) acc[i][j] = (f32x4){0.f, 0.f, 0.f, 0.f};

    // per-wave staging bases: A rows [w*32, w*32+32), B rows [w*NCT*4, ...)
    const u16* ga = Ab + (size_t)(bm + w * 32 + r8) * lda + acol + c8x;
    const u16* gb = Wb + (size_t)(jn0 + w * (NCT * 4) + r8) * 512 + c8x;

    auto stage = [&](int buf, int kt) {
        u16* la = sm + buf * HALF + (w * 32) * 64;
        u16* lb = sm + buf * HALF + ASZ + (w * (NCT * 4)) * 64;
#pragma unroll
        for (int j = 0; j < 4; ++j)
            gload16(ga + (size_t)j * 8 * lda + kt, la + j * 8 * 64);
#pragma unroll
        for (int j = 0; j < NCT / 2; ++j)
            gload16(gb + (size_t)j * 8 * 512 + kt, lb + j * 8 * 64);
    };
    auto compute = [&](int buf) {
        const u16* Ab_ = sm + buf * HALF;
        const u16* Bb_ = Ab_ + ASZ;
#pragma unroll
        for (int kk = 0; kk < 2; ++kk) {
            const int ca = ((kk * 4 + quad) ^ sx) << 3;   // swizzled read chunk
            short8 a0 = *(const short8*)&Ab_[(w * 32 + s) * 64 + ca];
            short8 a1 = *(const short8*)&Ab_[(w * 32 + 16 + s) * 64 + ca];
#pragma unroll
            for (int ct = 0; ct < NCT; ++ct) {
                short8 bf = *(const short8*)&Bb_[(ct * 16 + s) * 64 + ca];
                acc[0][ct] = MFMA16(a0, bf, acc[0][ct]);
                acc[1][ct] = MFMA16(a1, bf, acc[1][ct]);
            }
        }
    };

    // Pipeline: prologue stages tile0 into buf1; computes alternate 1,0,1,...
    stage(1, 0);
    __syncthreads();
#pragma unroll
    for (int it = 0; it < 7; ++it) {
        const int cur = 1 - (it & 1);
        stage(1 - cur, 64 * (it + 1));            // issue next-tile loads
        __builtin_amdgcn_sched_barrier(0);        // pin issue-before-compute
        compute(cur);
        __syncthreads();                          // drains prefetch; guards WAR
    }
    compute(0);

    if constexpr (MODE == MOUT) {
#pragma unroll
        for (int mt = 0; mt < 2; ++mt)
#pragma unroll
            for (int ct = 0; ct < NCT; ++ct) {
                const int jn = jn0 + ct * 16 + s;
#pragma unroll
                for (int r = 0; r < 4; ++r) {
                    const int row = bm + w * 32 + mt * 16 + quad * 4 + r;
                    outp[(size_t)row * 512 + jn] =
                        acc[mt][ct][r] + bias[jn] + bf2f(qkws_ro[(size_t)row * 1024 + jn]);
                }
            }
    } else {
        float rsum[2][NCT / 4][4];
        if constexpr (MODE == MQK) {
#pragma unroll
            for (int mt = 0; mt < 2; ++mt)
#pragma unroll
                for (int hg = 0; hg < NCT / 4; ++hg)
#pragma unroll
                    for (int r = 0; r < 4; ++r) rsum[mt][hg][r] = 0.f;
        }
        __syncthreads();   // final-buf reads (buf0) done; C overlays buf1
#pragma unroll
        for (int mt = 0; mt < 2; ++mt)
#pragma unroll
            for (int ct = 0; ct < NCT; ++ct) {
                const int jn = jn0 + ct * 16 + s;
                const float bj = bias[jn];
#pragma unroll
                for (int r = 0; r < 4; ++r) {
                    const int rowl = w * 32 + mt * 16 + quad * 4 + r;
                    float v = acc[mt][ct][r] + bj;
                    if constexpr (MODE == MVU) {
                        const int row = bm + rowl;
                        v *= kg[(((row >> 10) * 8 + (jn >> 6)) << 10) | (row & 1023)];
                    }
                    if constexpr (MODE == MQK) rsum[mt][ct >> 2][r] += v;
                    Cb[rowl * CST + ct * 16 + s] = f2bf(v);
                }
            }
        if constexpr (MODE == MQK) {
            // fused qs/ks: per-row sum over each 64-col head group
#pragma unroll
            for (int mt = 0; mt < 2; ++mt)
#pragma unroll
                for (int hg = 0; hg < NCT / 4; ++hg)
#pragma unroll
                    for (int r = 0; r < 4; ++r) {
                        float S = rsum[mt][hg][r];
                        S += __shfl_xor(S, 1);
                        S += __shfl_xor(S, 2);
                        S += __shfl_xor(S, 4);
                        S += __shfl_xor(S, 8);
                        if (s == 0) {
                            const int row = bm + w * 32 + mt * 16 + quad * 4 + r;
                            const int jj = jn0 + hg * 64;
                            float* dst = (jj < 512) ? qsout : ksout;
                            dst[((((row >> 10) << 3) | ((jj >> 6) & 7)) << 10) | (row & 1023)] = S;
                        }
                    }
        }
        __syncthreads();
        const int row = t >> 1, ch = (t & 1) * (NCT * 8);
        u16* dp = qkws + (size_t)(bm + row) * 1024 + (MODE == MVU ? 512 : 0) + jn0 + ch;
#pragma unroll
        for (int i = 0; i < NCT; ++i)
            *(uint4*)(dp + i * 8) = *(const uint4*)&Cb[row * CST + ch + i * 8];
    }
}

// ---------------------------------------------------------------------------
// stage_gemm (8-wave, r14 verbatim): softmax-stage as a chunked GEMM.
// Block = (128 n-rows, head h); grid 512; 512 threads. Wave w owns rows
// (w&3)*32..+32 and ct-half (w>>2)*4..+4 of each 128-m chunk.
//   STG=1: l=(q.wq+bq)*S,            wv=qs      -> qg
//   STG=2: l=(rs*(k.wk)+bk)*S, rs=qg, wv=qg*ks  -> kg
// ---------------------------------------------------------------------------
template <int STG>
__global__ __launch_bounds__(512) void stage_gemm(
    const u16* __restrict__ qkws, int qcol0,
    const u16* __restrict__ wmb, const float* __restrict__ biasv,
    const float* __restrict__ rowscale,
    const float* __restrict__ wv1, const float* __restrict__ wv2,
    float* __restrict__ outg)
{
    __shared__ u16 sm[24576];               // A 8192 | Bbuf0 8192 | Bbuf1 8192
    __shared__ float zp[2][128], wp[2][128];
    u16* const As = sm;

    const int t = threadIdx.x;
    const int w = t >> 6, lane = t & 63, s = lane & 15, quad = lane >> 4;
    const int sx = lane & 7;
    const int r8 = lane >> 3;
    const int c8x = ((lane & 7) ^ r8) << 3;         // swizzled source chunk (u16)
    const int wr = w & 3;                           // row group (32 rows)
    const int mg = w >> 2;                          // m-half group (4 ct)

    // XCD swizzle over 512 blocks
    const int flat = blockIdx.y * gridDim.x + blockIdx.x;
    const int swz = (flat & 7) * 64 + (flat >> 3);
    const int h = swz & 7, bx = swz >> 3;
    const int bm = bx * 128;                        // row in 8192-space
    const int bh = ((bm >> 10) << 3) + h;
    const int n0 = bm & 1023;

    // staging bases: wave w stages rows w*16..w*16+16 (A and B-chunk)
    const u16* gA = qkws + (size_t)(bm + w * 16 + r8) * 1024 + qcol0 + (h << 6) + c8x;
    const u16* gB = wmb + (size_t)(w * 16 + r8) * 64 + c8x;

    auto stageB = [&](int buf, int c) {
        u16* lb = sm + 8192 + buf * 8192 + (w * 16) * 64;
        const u16* g = gB + (size_t)c * 128 * 64;
#pragma unroll
        for (int j = 0; j < 2; ++j)
            gload16(g + (size_t)j * 8 * 64, lb + j * 8 * 64);
    };

    // prologue: A once + B chunk0 into buf1
#pragma unroll
    for (int j = 0; j < 2; ++j)
        gload16(gA + (size_t)j * 8 * 1024, As + (w * 16 + j * 8) * 64);
    stageB(1, 0);
    __syncthreads();

    // A fragments in registers for the whole kernel (rows wr*32..+32)
    short8 a[2][2];
#pragma unroll
    for (int nt = 0; nt < 2; ++nt)
#pragma unroll
        for (int kk = 0; kk < 2; ++kk)
            a[nt][kk] = *(const short8*)&As[(wr * 32 + nt * 16 + s) * 64 + (((kk * 4 + quad) ^ sx) << 3)];

    float rsf[2][4];
#pragma unroll
    for (int nt = 0; nt < 2; ++nt)
#pragma unroll
        for (int r = 0; r < 4; ++r) {
            if constexpr (STG == 2)
                rsf[nt][r] = rowscale[(bh << 10) + n0 + wr * 32 + nt * 16 + quad * 4 + r] * SCL2;
            else
                rsf[nt][r] = SCL2;
        }

    float z[2][4] = {}, wacc[2][4] = {};
    const int ct0 = mg * 4;                         // this wave's ct-half

#pragma unroll 1
    for (int c = 0; c < 8; ++c) {
        const int cur = 1 - (c & 1);
        if (c < 7) stageB(1 - cur, c + 1);          // issue next-chunk loads
        __builtin_amdgcn_sched_barrier(0);

        // bias / wv for this wave's ct-half (L2-hot)
        float bmv[4], wvv[4];
#pragma unroll
        for (int i = 0; i < 4; ++i) {
            const int m = c * 128 + (ct0 + i) * 16 + s;
            bmv[i] = biasv[m] * SCL2;
            float wv = wv1[(bh << 10) + m];
            if constexpr (STG == 2) wv *= wv2[(bh << 10) + m];
            wvv[i] = wv;
        }

        const u16* Bb = sm + 8192 + cur * 8192;
#pragma unroll
        for (int i = 0; i < 4; ++i) {
            const int ct = ct0 + i;
            const short8 b0 = *(const short8*)&Bb[(ct * 16 + s) * 64 + ((quad ^ sx) << 3)];
            const short8 b1 = *(const short8*)&Bb[(ct * 16 + s) * 64 + (((4 + quad) ^ sx) << 3)];
#pragma unroll
            for (int nt = 0; nt < 2; ++nt) {
                f32x4 acc = (f32x4){0.f, 0.f, 0.f, 0.f};
                acc = MFMA16(a[nt][0], b0, acc);
                acc = MFMA16(a[nt][1], b1, acc);
#pragma unroll
                for (int r = 0; r < 4; ++r) {
                    const float e = __builtin_amdgcn_exp2f(rsf[nt][r] * acc[r] + bmv[i]);
                    z[nt][r] += e;
                    wacc[nt][r] += e * wvv[i];
                }
            }
        }
        __syncthreads();                            // chunk consumed; WAR-safe
    }

    // reduce over the 16 m-lanes; s==0 writes the wave's partial plane
#pragma unroll
    for (int nt = 0; nt < 2; ++nt)
#pragma unroll
        for (int r = 0; r < 4; ++r) {
            float Z = z[nt][r], W = wacc[nt][r];
            for (int off = 1; off < 16; off <<= 1) {
                Z += __shfl_xor(Z, off);
                W += __shfl_xor(W, off);
            }
            if (s == 0) {
                const int rowl = wr * 32 + nt * 16 + quad * 4 + r;
                zp[mg][rowl] = Z;
                wp[mg][rowl] = W;
            }
        }
    __syncthreads();
    if (t < 128) {
        const float Z = zp[0][t] + zp[1][t];
        const float W = wp[0][t] + wp[1][t];
        outg[(bh << 10) + n0 + t] = W / Z;
    }
}

// ---------------------------------------------------------------------------
extern "C" void kernel_launch(void* const* d_in, const int* in_sizes, int n_in,
                              void* d_out, int out_size, void* d_ws, size_t ws_size,
                              hipStream_t stream)
{
    const float* x     = (const float*)d_in[0];
    const float* w_qkv = (const float*)d_in[1];
    const float* b_qkv = (const float*)d_in[2];
    const float* wq    = (const float*)d_in[3];
    const float* bq    = (const float*)d_in[4];
    const float* wk    = (const float*)d_in[5];
    const float* bk    = (const float*)d_in[6];
    const float* w_out = (const float*)d_in[7];
    const float* b_out = (const float*)d_in[8];
    float* out = (float*)d_out;

    // ws: qs|ks|qg|kg (65536 f32) | bf16: wqkv|wout|wq|wk|x | qk ws bf16
    float* qs = (float*)d_ws;
    float* ks = qs + 65536;
    float* qg = ks + 65536;
    float* kg = qg + 65536;
    u16* wsb   = (u16*)(kg + 65536);
    u16* wqkvb = wsb;
    u16* woutb = wqkvb + 786432;
    u16* wqb   = woutb + 262144;
    u16* wkb   = wqb + 65536;
    u16* xb    = wkb + 65536;
    u16* qkws  = xb + 4194304;

    // 5,373,952 f32 -> bf16 (weights + x), 4 elems/thread
    conv_kernel<<<5248, 256, 0, stream>>>(w_qkv, w_out, wq, wk, x, wsb);
    // QK: qk = x @ w_qkv[0:1024]^T + b_qkv  (128x128 tile) + fused qs/ks
    gemm_k<MQK, 8><<<dim3(64, 8), 256, 0, stream>>>(
        xb, 512, 0, wqkvb, b_qkv, nullptr, nullptr, qkws, nullptr, qs, ks);
    // stage 1 -> qg   (launched TWICE -- idempotent probe, see header)
    stage_gemm<1><<<dim3(64, 8), 512, 0, stream>>>(
        qkws, 0, wqb, bq, nullptr, qs, nullptr, qg);
    stage_gemm<1><<<dim3(64, 8), 512, 0, stream>>>(
        qkws, 0, wqb, bq, nullptr, qs, nullptr, qg);
    // stage 2 -> kg   (launched TWICE -- idempotent probe)
    stage_gemm<2><<<dim3(64, 8), 512, 0, stream>>>(
        qkws, 512, wkb, bk, qg, qg, ks, kg);
    stage_gemm<2><<<dim3(64, 8), 512, 0, stream>>>(
        qkws, 512, wkb, bk, qg, qg, ks, kg);
    // VU: U = (x @ w_qkv[1024:]^T + bv) * kg  (into k-half of qk ws)
    gemm_k<MVU, 4><<<dim3(64, 8), 256, 0, stream>>>(
        xb, 512, 0, wqkvb + (size_t)1024 * 512, b_qkv + 1024, kg, nullptr, qkws,
        nullptr, nullptr, nullptr);
    // OUT: out = U @ w_out^T + b_out + qo
    gemm_k<MOUT, 4><<<dim3(64, 8), 256, 0, stream>>>(
        qkws, 1024, 512, woutb, b_out, nullptr, qkws, nullptr, out, nullptr, nullptr);
}

// Round 12
// 170.383 us; speedup vs baseline: 1.2331x; 1.2331x over previous
//
#include <hip/hip_runtime.h>

// Fastformer additive attention, MI355X (round 19):
//   - Probe (r18) measured: stages = 22.5us EACH (45 of ~67 controllable us).
//     Evidence across r11/r13/r14/r17: stage time responds ONLY to occupancy
//     (r13->r14: 2->4 waves/SIMD = 1.23x), not to scheduling.
//   - Change: stage_gemm occupancy package: B-chunk 64 rows (LDS 50->34KB),
//     __launch_bounds__(512,6) (VGPR cap ~84, est live ~70, no spill),
//     -> 3 blocks/CU x 8 waves = 6 waves/SIMD + 3-way barrier diversity.
//     16 chunks of 64 m-rows; wave w: rows (w&3)*32..+32, ct pair (w>>2)*2.
//   - conv / gemm_k / launches: r14 verbatim.
// Pipeline: conv -> QK(+qsks) -> stage1 -> stage2 -> VU -> OUT  (6 launches)

#define SCL2 0.1803368801f   /* 0.125 * log2(e) */
typedef unsigned short u16;
typedef __attribute__((ext_vector_type(8))) short short8;   // 8 bf16 = 4 VGPR
typedef __attribute__((ext_vector_type(4))) float f32x4;

#define MFMA16(a, b, c) __builtin_amdgcn_mfma_f32_16x16x32_bf16((a), (b), (c), 0, 0, 0)

__device__ __forceinline__ float bf2f(u16 u) {
    union { unsigned int i; float f; } v; v.i = ((unsigned int)u) << 16; return v.f;
}
__device__ __forceinline__ u16 f2bf(float f) {
    union { float f; unsigned int i; } v; v.f = f;
    unsigned int x = v.i;
    return (u16)((x + 0x7FFFu + ((x >> 16) & 1u)) >> 16);
}

// async global->LDS, 16B per lane; LDS dest = wave-uniform base + lane*16
__device__ __forceinline__ void gload16(const u16* g, u16* l) {
    __builtin_amdgcn_global_load_lds(
        (__attribute__((address_space(1))) void*)(void*)g,
        (__attribute__((address_space(3))) void*)l, 16, 0, 0);
}

// ---------------------------------------------------------------------------
// f32 -> bf16: w_qkv | w_out | wq | wk | x   (contiguous ws block)
// ---------------------------------------------------------------------------
__global__ __launch_bounds__(256) void conv_kernel(
    const float* __restrict__ w_qkv, const float* __restrict__ w_out,
    const float* __restrict__ wq, const float* __restrict__ wk,
    const float* __restrict__ x, u16* __restrict__ wsb)
{
    const int idx = (blockIdx.x * 256 + threadIdx.x) * 4;
    const float* src; int off;
    if      (idx < 786432)  { src = w_qkv; off = idx; }
    else if (idx < 1048576) { src = w_out; off = idx - 786432; }
    else if (idx < 1114112) { src = wq;    off = idx - 1048576; }
    else if (idx < 1179648) { src = wk;    off = idx - 1114112; }
    else                    { src = x;     off = idx - 1179648; }
    float4 v = *(const float4*)(src + off);
    ushort4 o; o.x = f2bf(v.x); o.y = f2bf(v.y); o.z = f2bf(v.z); o.w = f2bf(v.w);
    *(ushort4*)(wsb + idx) = o;
}

// ---------------------------------------------------------------------------
// MFMA GEMM (round-9 verbatim): tile 128M x (NCT*16)N, BK=64, K=512, 4 waves.
// Double-buffered gload_lds staging (linear LDS dest, source chunk swizzled
// with (lane&7)^(lane>>3)); fragment reads XOR chunk idx with (row&7).
// K-loop: stage(next buf) -> sched_barrier -> compute(cur) -> syncthreads.
// Final compute reads buf0; C bounce (padded stride) overlays buf1.
// ---------------------------------------------------------------------------
#define MQK 0
#define MVU 1
#define MOUT 2

template <int MODE, int NCT>
__global__ __launch_bounds__(256) void gemm_k(
    const u16* __restrict__ Ab, int lda, int acol,
    const u16* __restrict__ Wb, const float* __restrict__ bias,
    const float* __restrict__ kg, const u16* __restrict__ qkws_ro,
    u16* __restrict__ qkws, float* __restrict__ outp,
    float* __restrict__ qsout, float* __restrict__ ksout)
{
    constexpr int BN = NCT * 16;            // tile N
    constexpr int CST = BN + 8;             // padded bounce stride (u16)
    constexpr int ASZ = 128 * 64;           // A elems per buffer
    constexpr int BSZ = BN * 64;            // B elems per buffer
    constexpr int HALF = ASZ + BSZ;         // one double-buffer half
    constexpr int CELEM = 128 * CST;
    constexpr int SMSZ = (2 * HALF > HALF + CELEM) ? 2 * HALF : HALF + CELEM;
    __shared__ u16 sm[SMSZ];
    u16* const Cb = sm + HALF;              // C bounce overlays buf1 only

    const int t = threadIdx.x;
    const int w = t >> 6, lane = t & 63, s = lane & 15, quad = lane >> 4;
    const int sx = lane & 7;                // row&7 of every fragment row read

    // T1: bijective XCD swizzle (nwg % 8 == 0)
    const int nwgy = gridDim.y;
    const int nwg = gridDim.x * nwgy;
    const int flat = blockIdx.y * gridDim.x + blockIdx.x;
    const int swz = (flat & 7) * (nwg >> 3) + (flat >> 3);
    const int by = swz % nwgy, bx = swz / nwgy;
    const int bm = bx * 128, jn0 = by * BN;

    const int r8 = lane >> 3;                       // staged row within 8-row group
    const int c8x = ((lane & 7) ^ r8) << 3;         // swizzled source chunk (u16)

    f32x4 acc[2][NCT];
#pragma unroll
    for (int i = 0; i < 2; ++i)
#pragma unroll
        for (int j = 0; j < NCT; ++j) acc[i][j] = (f32x4){0.f, 0.f, 0.f, 0.f};

    // per-wave staging bases: A rows [w*32, w*32+32), B rows [w*NCT*4, ...)
    const u16* ga = Ab + (size_t)(bm + w * 32 + r8) * lda + acol + c8x;
    const u16* gb = Wb + (size_t)(jn0 + w * (NCT * 4) + r8) * 512 + c8x;

    auto stage = [&](int buf, int kt) {
        u16* la = sm + buf * HALF + (w * 32) * 64;
        u16* lb = sm + buf * HALF + ASZ + (w * (NCT * 4)) * 64;
#pragma unroll
        for (int j = 0; j < 4; ++j)
            gload16(ga + (size_t)j * 8 * lda + kt, la + j * 8 * 64);
#pragma unroll
        for (int j = 0; j < NCT / 2; ++j)
            gload16(gb + (size_t)j * 8 * 512 + kt, lb + j * 8 * 64);
    };
    auto compute = [&](int buf) {
        const u16* Ab_ = sm + buf * HALF;
        const u16* Bb_ = Ab_ + ASZ;
#pragma unroll
        for (int kk = 0; kk < 2; ++kk) {
            const int ca = ((kk * 4 + quad) ^ sx) << 3;   // swizzled read chunk
            short8 a0 = *(const short8*)&Ab_[(w * 32 + s) * 64 + ca];
            short8 a1 = *(const short8*)&Ab_[(w * 32 + 16 + s) * 64 + ca];
#pragma unroll
            for (int ct = 0; ct < NCT; ++ct) {
                short8 bf = *(const short8*)&Bb_[(ct * 16 + s) * 64 + ca];
                acc[0][ct] = MFMA16(a0, bf, acc[0][ct]);
                acc[1][ct] = MFMA16(a1, bf, acc[1][ct]);
            }
        }
    };

    // Pipeline: prologue stages tile0 into buf1; computes alternate 1,0,1,...
    stage(1, 0);
    __syncthreads();
#pragma unroll
    for (int it = 0; it < 7; ++it) {
        const int cur = 1 - (it & 1);
        stage(1 - cur, 64 * (it + 1));            // issue next-tile loads
        __builtin_amdgcn_sched_barrier(0);        // pin issue-before-compute
        compute(cur);
        __syncthreads();                          // drains prefetch; guards WAR
    }
    compute(0);

    if constexpr (MODE == MOUT) {
#pragma unroll
        for (int mt = 0; mt < 2; ++mt)
#pragma unroll
            for (int ct = 0; ct < NCT; ++ct) {
                const int jn = jn0 + ct * 16 + s;
#pragma unroll
                for (int r = 0; r < 4; ++r) {
                    const int row = bm + w * 32 + mt * 16 + quad * 4 + r;
                    outp[(size_t)row * 512 + jn] =
                        acc[mt][ct][r] + bias[jn] + bf2f(qkws_ro[(size_t)row * 1024 + jn]);
                }
            }
    } else {
        float rsum[2][NCT / 4][4];
        if constexpr (MODE == MQK) {
#pragma unroll
            for (int mt = 0; mt < 2; ++mt)
#pragma unroll
                for (int hg = 0; hg < NCT / 4; ++hg)
#pragma unroll
                    for (int r = 0; r < 4; ++r) rsum[mt][hg][r] = 0.f;
        }
        __syncthreads();   // final-buf reads (buf0) done; C overlays buf1
#pragma unroll
        for (int mt = 0; mt < 2; ++mt)
#pragma unroll
            for (int ct = 0; ct < NCT; ++ct) {
                const int jn = jn0 + ct * 16 + s;
                const float bj = bias[jn];
#pragma unroll
                for (int r = 0; r < 4; ++r) {
                    const int rowl = w * 32 + mt * 16 + quad * 4 + r;
                    float v = acc[mt][ct][r] + bj;
                    if constexpr (MODE == MVU) {
                        const int row = bm + rowl;
                        v *= kg[(((row >> 10) * 8 + (jn >> 6)) << 10) | (row & 1023)];
                    }
                    if constexpr (MODE == MQK) rsum[mt][ct >> 2][r] += v;
                    Cb[rowl * CST + ct * 16 + s] = f2bf(v);
                }
            }
        if constexpr (MODE == MQK) {
            // fused qs/ks: per-row sum over each 64-col head group
#pragma unroll
            for (int mt = 0; mt < 2; ++mt)
#pragma unroll
                for (int hg = 0; hg < NCT / 4; ++hg)
#pragma unroll
                    for (int r = 0; r < 4; ++r) {
                        float S = rsum[mt][hg][r];
                        S += __shfl_xor(S, 1);
                        S += __shfl_xor(S, 2);
                        S += __shfl_xor(S, 4);
                        S += __shfl_xor(S, 8);
                        if (s == 0) {
                            const int row = bm + w * 32 + mt * 16 + quad * 4 + r;
                            const int jj = jn0 + hg * 64;
                            float* dst = (jj < 512) ? qsout : ksout;
                            dst[((((row >> 10) << 3) | ((jj >> 6) & 7)) << 10) | (row & 1023)] = S;
                        }
                    }
        }
        __syncthreads();
        const int row = t >> 1, ch = (t & 1) * (NCT * 8);
        u16* dp = qkws + (size_t)(bm + row) * 1024 + (MODE == MVU ? 512 : 0) + jn0 + ch;
#pragma unroll
        for (int i = 0; i < NCT; ++i)
            *(uint4*)(dp + i * 8) = *(const uint4*)&Cb[row * CST + ch + i * 8];
    }
}

// ---------------------------------------------------------------------------
// stage_gemm (8-wave, 16x64-chunk, 3 blocks/CU): softmax-stage as a chunked
// GEMM. Block = (128 n-rows, head h); grid 512; 512 threads;
// __launch_bounds__(512,6) caps VGPR (~84) so 3 blocks/CU co-reside
// -> 6 waves/SIMD. Wave w: rows (w&3)*32..+32, ct pair (w>>2)*2 of each
// 64-m chunk. B dbuf 2x8KB; A 16KB staged once; chunk loop unroll 1 (r12).
//   STG=1: l=(q.wq+bq)*S,            wv=qs      -> qg
//   STG=2: l=(rs*(k.wk)+bk)*S, rs=qg, wv=qg*ks  -> kg
// ---------------------------------------------------------------------------
template <int STG>
__global__ __launch_bounds__(512, 6) void stage_gemm(
    const u16* __restrict__ qkws, int qcol0,
    const u16* __restrict__ wmb, const float* __restrict__ biasv,
    const float* __restrict__ rowscale,
    const float* __restrict__ wv1, const float* __restrict__ wv2,
    float* __restrict__ outg)
{
    __shared__ u16 sm[8192 + 2 * 4096];     // A 16KB | B buf0 8KB | buf1 8KB
    __shared__ float zp[2][128], wp[2][128];
    u16* const As = sm;

    const int t = threadIdx.x;
    const int w = t >> 6, lane = t & 63, s = lane & 15, quad = lane >> 4;
    const int sx = lane & 7;
    const int r8 = lane >> 3;
    const int c8x = ((lane & 7) ^ r8) << 3;         // swizzled source chunk (u16)
    const int wr = w & 3;                           // row group (32 rows)
    const int mg = w >> 2;                          // m-half group (2 ct of 4)

    // XCD swizzle over 512 blocks
    const int flat = blockIdx.y * gridDim.x + blockIdx.x;
    const int swz = (flat & 7) * 64 + (flat >> 3);
    const int h = swz & 7, bx = swz >> 3;
    const int bm = bx * 128;                        // row in 8192-space
    const int bh = ((bm >> 10) << 3) + h;
    const int n0 = bm & 1023;

    // staging bases: A rows w*16..+16 (2 gload16); B-chunk rows w*8..+8 (1)
    const u16* gA = qkws + (size_t)(bm + w * 16 + r8) * 1024 + qcol0 + (h << 6) + c8x;
    const u16* gB = wmb + (size_t)(w * 8 + r8) * 64 + c8x;

    auto stageB = [&](int buf, int c) {
        u16* lb = sm + 8192 + buf * 4096 + (w * 8) * 64;
        gload16(gB + (size_t)c * 64 * 64, lb);
    };

    // prologue: A once + B chunk0 into buf1
#pragma unroll
    for (int j = 0; j < 2; ++j)
        gload16(gA + (size_t)j * 8 * 1024, As + (w * 16 + j * 8) * 64);
    stageB(1, 0);
    __syncthreads();

    // A fragments in registers for the whole kernel (rows wr*32..+32)
    short8 a[2][2];
#pragma unroll
    for (int nt = 0; nt < 2; ++nt)
#pragma unroll
        for (int kk = 0; kk < 2; ++kk)
            a[nt][kk] = *(const short8*)&As[(wr * 32 + nt * 16 + s) * 64 + (((kk * 4 + quad) ^ sx) << 3)];

    float rsf[2][4];
#pragma unroll
    for (int nt = 0; nt < 2; ++nt)
#pragma unroll
        for (int r = 0; r < 4; ++r) {
            if constexpr (STG == 2)
                rsf[nt][r] = rowscale[(bh << 10) + n0 + wr * 32 + nt * 16 + quad * 4 + r] * SCL2;
            else
                rsf[nt][r] = SCL2;
        }

    float z[2][4] = {}, wacc[2][4] = {};
    const int ct0 = mg * 2;                         // this wave's ct pair

#pragma unroll 1
    for (int c = 0; c < 16; ++c) {
        const int cur = 1 - (c & 1);
        if (c < 15) stageB(1 - cur, c + 1);         // issue next-chunk load
        __builtin_amdgcn_sched_barrier(0);

        // bias / wv for this wave's ct pair (L2-hot)
        float bmv[2], wvv[2];
#pragma unroll
        for (int i = 0; i < 2; ++i) {
            const int m = c * 64 + (ct0 + i) * 16 + s;
            bmv[i] = biasv[m] * SCL2;
            float wv = wv1[(bh << 10) + m];
            if constexpr (STG == 2) wv *= wv2[(bh << 10) + m];
            wvv[i] = wv;
        }

        const u16* Bb = sm + 8192 + cur * 4096;
#pragma unroll
        for (int i = 0; i < 2; ++i) {
            const int ct = ct0 + i;
            const short8 b0 = *(const short8*)&Bb[(ct * 16 + s) * 64 + ((quad ^ sx) << 3)];
            const short8 b1 = *(const short8*)&Bb[(ct * 16 + s) * 64 + (((4 + quad) ^ sx) << 3)];
#pragma unroll
            for (int nt = 0; nt < 2; ++nt) {
                f32x4 acc = (f32x4){0.f, 0.f, 0.f, 0.f};
                acc = MFMA16(a[nt][0], b0, acc);
                acc = MFMA16(a[nt][1], b1, acc);
#pragma unroll
                for (int r = 0; r < 4; ++r) {
                    const float e = __builtin_amdgcn_exp2f(rsf[nt][r] * acc[r] + bmv[i]);
                    z[nt][r] += e;
                    wacc[nt][r] += e * wvv[i];
                }
            }
        }
        __syncthreads();                            // chunk consumed; WAR-safe
    }

    // reduce over the 16 m-lanes; s==0 writes the wave's partial plane
#pragma unroll
    for (int nt = 0; nt < 2; ++nt)
#pragma unroll
        for (int r = 0; r < 4; ++r) {
            float Z = z[nt][r], W = wacc[nt][r];
            for (int off = 1; off < 16; off <<= 1) {
                Z += __shfl_xor(Z, off);
                W += __shfl_xor(W, off);
            }
            if (s == 0) {
                const int rowl = wr * 32 + nt * 16 + quad * 4 + r;
                zp[mg][rowl] = Z;
                wp[mg][rowl] = W;
            }
        }
    __syncthreads();
    if (t < 128) {
        const float Z = zp[0][t] + zp[1][t];
        const float W = wp[0][t] + wp[1][t];
        outg[(bh << 10) + n0 + t] = W / Z;
    }
}

// ---------------------------------------------------------------------------
extern "C" void kernel_launch(void* const* d_in, const int* in_sizes, int n_in,
                              void* d_out, int out_size, void* d_ws, size_t ws_size,
                              hipStream_t stream)
{
    const float* x     = (const float*)d_in[0];
    const float* w_qkv = (const float*)d_in[1];
    const float* b_qkv = (const float*)d_in[2];
    const float* wq    = (const float*)d_in[3];
    const float* bq    = (const float*)d_in[4];
    const float* wk    = (const float*)d_in[5];
    const float* bk    = (const float*)d_in[6];
    const float* w_out = (const float*)d_in[7];
    const float* b_out = (const float*)d_in[8];
    float* out = (float*)d_out;

    // ws: qs|ks|qg|kg (65536 f32) | bf16: wqkv|wout|wq|wk|x | qk ws bf16
    float* qs = (float*)d_ws;
    float* ks = qs + 65536;
    float* qg = ks + 65536;
    float* kg = qg + 65536;
    u16* wsb   = (u16*)(kg + 65536);
    u16* wqkvb = wsb;
    u16* woutb = wqkvb + 786432;
    u16* wqb   = woutb + 262144;
    u16* wkb   = wqb + 65536;
    u16* xb    = wkb + 65536;
    u16* qkws  = xb + 4194304;

    // 5,373,952 f32 -> bf16 (weights + x), 4 elems/thread
    conv_kernel<<<5248, 256, 0, stream>>>(w_qkv, w_out, wq, wk, x, wsb);
    // QK: qk = x @ w_qkv[0:1024]^T + b_qkv  (128x128 tile) + fused qs/ks
    gemm_k<MQK, 8><<<dim3(64, 8), 256, 0, stream>>>(
        xb, 512, 0, wqkvb, b_qkv, nullptr, nullptr, qkws, nullptr, qs, ks);
    // stage 1 -> qg
    stage_gemm<1><<<dim3(64, 8), 512, 0, stream>>>(
        qkws, 0, wqb, bq, nullptr, qs, nullptr, qg);
    // stage 2 -> kg
    stage_gemm<2><<<dim3(64, 8), 512, 0, stream>>>(
        qkws, 512, wkb, bk, qg, qg, ks, kg);
    // VU: U = (x @ w_qkv[1024:]^T + bv) * kg  (into k-half of qk ws)
    gemm_k<MVU, 4><<<dim3(64, 8), 256, 0, stream>>>(
        xb, 512, 0, wqkvb + (size_t)1024 * 512, b_qkv + 1024, kg, nullptr, qkws,
        nullptr, nullptr, nullptr);
    // OUT: out = U @ w_out^T + b_out + qo
    gemm_k<MOUT, 4><<<dim3(64, 8), 256, 0, stream>>>(
        qkws, 1024, 512, woutb, b_out, nullptr, qkws, nullptr, out, nullptr, nullptr);
}

// Round 13
// 163.254 us; speedup vs baseline: 1.2870x; 1.0437x over previous
//
#include <hip/hip_runtime.h>

// Fastformer additive attention, MI355X (round 20):
//   - Theory (explains r11/r13/r14/r17/r19): stage chunk loop had VMEM
//     bias/wv loads issued AFTER the B-prefetch; vmcnt is ordered, so the
//     compiler's wait before using bias DRAINED the prefetch every chunk ->
//     full L2 RTT exposed 8x/block. Fix: bias/wv1/wv2 staged to LDS in the
//     prologue (gload16); chunk loop is VMEM-free except B-prefetch ->
//     counted vmcnt(2) + single s_barrier per chunk, TRI-buffered B
//     (WAR-safe: N=3 >= one-barrier skew + 1). 8 chunks of 128 kept.
//   - conv / gemm_k (QK, VU, OUT): r14 verbatim. Base 163.2us.
// Pipeline: conv -> QK(+qsks) -> stage1 -> stage2 -> VU -> OUT  (6 launches)

#define SCL2 0.1803368801f   /* 0.125 * log2(e) */
typedef unsigned short u16;
typedef __attribute__((ext_vector_type(8))) short short8;   // 8 bf16 = 4 VGPR
typedef __attribute__((ext_vector_type(4))) float f32x4;

#define MFMA16(a, b, c) __builtin_amdgcn_mfma_f32_16x16x32_bf16((a), (b), (c), 0, 0, 0)

__device__ __forceinline__ float bf2f(u16 u) {
    union { unsigned int i; float f; } v; v.i = ((unsigned int)u) << 16; return v.f;
}
__device__ __forceinline__ u16 f2bf(float f) {
    union { float f; unsigned int i; } v; v.f = f;
    unsigned int x = v.i;
    return (u16)((x + 0x7FFFu + ((x >> 16) & 1u)) >> 16);
}

// async global->LDS, 16B per lane; LDS dest = wave-uniform base + lane*16
__device__ __forceinline__ void gload16(const u16* g, u16* l) {
    __builtin_amdgcn_global_load_lds(
        (__attribute__((address_space(1))) void*)(void*)g,
        (__attribute__((address_space(3))) void*)l, 16, 0, 0);
}
__device__ __forceinline__ void gloadf(const float* g, float* l) {
    __builtin_amdgcn_global_load_lds(
        (__attribute__((address_space(1))) void*)(void*)g,
        (__attribute__((address_space(3))) void*)l, 16, 0, 0);
}

// ---------------------------------------------------------------------------
// f32 -> bf16: w_qkv | w_out | wq | wk | x   (contiguous ws block)
// ---------------------------------------------------------------------------
__global__ __launch_bounds__(256) void conv_kernel(
    const float* __restrict__ w_qkv, const float* __restrict__ w_out,
    const float* __restrict__ wq, const float* __restrict__ wk,
    const float* __restrict__ x, u16* __restrict__ wsb)
{
    const int idx = (blockIdx.x * 256 + threadIdx.x) * 4;
    const float* src; int off;
    if      (idx < 786432)  { src = w_qkv; off = idx; }
    else if (idx < 1048576) { src = w_out; off = idx - 786432; }
    else if (idx < 1114112) { src = wq;    off = idx - 1048576; }
    else if (idx < 1179648) { src = wk;    off = idx - 1114112; }
    else                    { src = x;     off = idx - 1179648; }
    float4 v = *(const float4*)(src + off);
    ushort4 o; o.x = f2bf(v.x); o.y = f2bf(v.y); o.z = f2bf(v.z); o.w = f2bf(v.w);
    *(ushort4*)(wsb + idx) = o;
}

// ---------------------------------------------------------------------------
// MFMA GEMM (round-9/14 verbatim): tile 128M x (NCT*16)N, BK=64, K=512.
// Double-buffered gload_lds staging (linear LDS dest, source chunk swizzled
// with (lane&7)^(lane>>3)); fragment reads XOR chunk idx with (row&7).
// K-loop: stage(next buf) -> sched_barrier -> compute(cur) -> syncthreads.
// Final compute reads buf0; C bounce (padded stride) overlays buf1.
// ---------------------------------------------------------------------------
#define MQK 0
#define MVU 1
#define MOUT 2

template <int MODE, int NCT>
__global__ __launch_bounds__(256) void gemm_k(
    const u16* __restrict__ Ab, int lda, int acol,
    const u16* __restrict__ Wb, const float* __restrict__ bias,
    const float* __restrict__ kg, const u16* __restrict__ qkws_ro,
    u16* __restrict__ qkws, float* __restrict__ outp,
    float* __restrict__ qsout, float* __restrict__ ksout)
{
    constexpr int BN = NCT * 16;            // tile N
    constexpr int CST = BN + 8;             // padded bounce stride (u16)
    constexpr int ASZ = 128 * 64;           // A elems per buffer
    constexpr int BSZ = BN * 64;            // B elems per buffer
    constexpr int HALF = ASZ + BSZ;         // one double-buffer half
    constexpr int CELEM = 128 * CST;
    constexpr int SMSZ = (2 * HALF > HALF + CELEM) ? 2 * HALF : HALF + CELEM;
    __shared__ u16 sm[SMSZ];
    u16* const Cb = sm + HALF;              // C bounce overlays buf1 only

    const int t = threadIdx.x;
    const int w = t >> 6, lane = t & 63, s = lane & 15, quad = lane >> 4;
    const int sx = lane & 7;                // row&7 of every fragment row read

    // T1: bijective XCD swizzle (nwg % 8 == 0)
    const int nwgy = gridDim.y;
    const int nwg = gridDim.x * nwgy;
    const int flat = blockIdx.y * gridDim.x + blockIdx.x;
    const int swz = (flat & 7) * (nwg >> 3) + (flat >> 3);
    const int by = swz % nwgy, bx = swz / nwgy;
    const int bm = bx * 128, jn0 = by * BN;

    const int r8 = lane >> 3;                       // staged row within 8-row group
    const int c8x = ((lane & 7) ^ r8) << 3;         // swizzled source chunk (u16)

    f32x4 acc[2][NCT];
#pragma unroll
    for (int i = 0; i < 2; ++i)
#pragma unroll
        for (int j = 0; j < NCT; ++j) acc[i][j] = (f32x4){0.f, 0.f, 0.f, 0.f};

    // per-wave staging bases: A rows [w*32, w*32+32), B rows [w*NCT*4, ...)
    const u16* ga = Ab + (size_t)(bm + w * 32 + r8) * lda + acol + c8x;
    const u16* gb = Wb + (size_t)(jn0 + w * (NCT * 4) + r8) * 512 + c8x;

    auto stage = [&](int buf, int kt) {
        u16* la = sm + buf * HALF + (w * 32) * 64;
        u16* lb = sm + buf * HALF + ASZ + (w * (NCT * 4)) * 64;
#pragma unroll
        for (int j = 0; j < 4; ++j)
            gload16(ga + (size_t)j * 8 * lda + kt, la + j * 8 * 64);
#pragma unroll
        for (int j = 0; j < NCT / 2; ++j)
            gload16(gb + (size_t)j * 8 * 512 + kt, lb + j * 8 * 64);
    };
    auto compute = [&](int buf) {
        const u16* Ab_ = sm + buf * HALF;
        const u16* Bb_ = Ab_ + ASZ;
#pragma unroll
        for (int kk = 0; kk < 2; ++kk) {
            const int ca = ((kk * 4 + quad) ^ sx) << 3;   // swizzled read chunk
            short8 a0 = *(const short8*)&Ab_[(w * 32 + s) * 64 + ca];
            short8 a1 = *(const short8*)&Ab_[(w * 32 + 16 + s) * 64 + ca];
#pragma unroll
            for (int ct = 0; ct < NCT; ++ct) {
                short8 bf = *(const short8*)&Bb_[(ct * 16 + s) * 64 + ca];
                acc[0][ct] = MFMA16(a0, bf, acc[0][ct]);
                acc[1][ct] = MFMA16(a1, bf, acc[1][ct]);
            }
        }
    };

    // Pipeline: prologue stages tile0 into buf1; computes alternate 1,0,1,...
    stage(1, 0);
    __syncthreads();
#pragma unroll
    for (int it = 0; it < 7; ++it) {
        const int cur = 1 - (it & 1);
        stage(1 - cur, 64 * (it + 1));            // issue next-tile loads
        __builtin_amdgcn_sched_barrier(0);        // pin issue-before-compute
        compute(cur);
        __syncthreads();                          // drains prefetch; guards WAR
    }
    compute(0);

    if constexpr (MODE == MOUT) {
#pragma unroll
        for (int mt = 0; mt < 2; ++mt)
#pragma unroll
            for (int ct = 0; ct < NCT; ++ct) {
                const int jn = jn0 + ct * 16 + s;
#pragma unroll
                for (int r = 0; r < 4; ++r) {
                    const int row = bm + w * 32 + mt * 16 + quad * 4 + r;
                    outp[(size_t)row * 512 + jn] =
                        acc[mt][ct][r] + bias[jn] + bf2f(qkws_ro[(size_t)row * 1024 + jn]);
                }
            }
    } else {
        float rsum[2][NCT / 4][4];
        if constexpr (MODE == MQK) {
#pragma unroll
            for (int mt = 0; mt < 2; ++mt)
#pragma unroll
                for (int hg = 0; hg < NCT / 4; ++hg)
#pragma unroll
                    for (int r = 0; r < 4; ++r) rsum[mt][hg][r] = 0.f;
        }
        __syncthreads();   // final-buf reads (buf0) done; C overlays buf1
#pragma unroll
        for (int mt = 0; mt < 2; ++mt)
#pragma unroll
            for (int ct = 0; ct < NCT; ++ct) {
                const int jn = jn0 + ct * 16 + s;
                const float bj = bias[jn];
#pragma unroll
                for (int r = 0; r < 4; ++r) {
                    const int rowl = w * 32 + mt * 16 + quad * 4 + r;
                    float v = acc[mt][ct][r] + bj;
                    if constexpr (MODE == MVU) {
                        const int row = bm + rowl;
                        v *= kg[(((row >> 10) * 8 + (jn >> 6)) << 10) | (row & 1023)];
                    }
                    if constexpr (MODE == MQK) rsum[mt][ct >> 2][r] += v;
                    Cb[rowl * CST + ct * 16 + s] = f2bf(v);
                }
            }
        if constexpr (MODE == MQK) {
            // fused qs/ks: per-row sum over each 64-col head group
#pragma unroll
            for (int mt = 0; mt < 2; ++mt)
#pragma unroll
                for (int hg = 0; hg < NCT / 4; ++hg)
#pragma unroll
                    for (int r = 0; r < 4; ++r) {
                        float S = rsum[mt][hg][r];
                        S += __shfl_xor(S, 1);
                        S += __shfl_xor(S, 2);
                        S += __shfl_xor(S, 4);
                        S += __shfl_xor(S, 8);
                        if (s == 0) {
                            const int row = bm + w * 32 + mt * 16 + quad * 4 + r;
                            const int jj = jn0 + hg * 64;
                            float* dst = (jj < 512) ? qsout : ksout;
                            dst[((((row >> 10) << 3) | ((jj >> 6) & 7)) << 10) | (row & 1023)] = S;
                        }
                    }
        }
        __syncthreads();
        const int row = t >> 1, ch = (t & 1) * (NCT * 8);
        u16* dp = qkws + (size_t)(bm + row) * 1024 + (MODE == MVU ? 512 : 0) + jn0 + ch;
#pragma unroll
        for (int i = 0; i < NCT; ++i)
            *(uint4*)(dp + i * 8) = *(const uint4*)&Cb[row * CST + ch + i * 8];
    }
}

// ---------------------------------------------------------------------------
// stage_gemm (8-wave, VMEM-free chunk loop, tri-buffered B):
// Block = (128 n-rows, head h); grid 512; 512 threads. Wave w owns rows
// (w&3)*32..+32 and ct-half (w>>2)*4..+4 of each 128-m chunk.
// Prologue: A tile (gload16), bias/wv1/wv2 vectors -> LDS (gloadf), B chunk0.
// Chunk loop: issue B(c+1)->buf (c+1)%3 ; s_waitcnt vmcnt(2) [only B loads
// in vmcnt!] ; s_barrier ; sched_barrier ; bias/wv via ds_read ; compute.
// Tri-buffer WAR-safe (one-barrier skew). Loop unroll 1 (r12 lesson).
//   STG=1: l=(q.wq+bq)*S,             wv=qs      -> qg
//   STG=2: l=(qg*(k.wk)+bk)*S,        wv=qg*ks   -> kg  (rowscale=wv1L slice)
// ---------------------------------------------------------------------------
template <int STG>
__global__ __launch_bounds__(512) void stage_gemm(
    const u16* __restrict__ qkws, int qcol0,
    const u16* __restrict__ wmb, const float* __restrict__ biasv,
    const float* __restrict__ wv1, const float* __restrict__ wv2,
    float* __restrict__ outg)
{
    __shared__ u16 As[128 * 64];                    // 16 KB
    __shared__ u16 Bs[3][128 * 64];                 // 48 KB tri-buffer
    __shared__ float biasL[1024];                   // 4 KB
    __shared__ float wv1L[1024];                    // 4 KB
    __shared__ float wv2L[(STG == 2) ? 1024 : 4];   // 4 KB (STG2)
    __shared__ float zp[2][128], wp[2][128];

    const int t = threadIdx.x;
    const int w = t >> 6, lane = t & 63, s = lane & 15, quad = lane >> 4;
    const int sx = lane & 7;
    const int r8 = lane >> 3;
    const int c8x = ((lane & 7) ^ r8) << 3;         // swizzled source chunk (u16)
    const int wr = w & 3;                           // row group (32 rows)
    const int mg = w >> 2;                          // m-half group (4 ct)

    // XCD swizzle over 512 blocks
    const int flat = blockIdx.y * gridDim.x + blockIdx.x;
    const int swz = (flat & 7) * 64 + (flat >> 3);
    const int h = swz & 7, bx = swz >> 3;
    const int bm = bx * 128;                        // row in 8192-space
    const int bh = ((bm >> 10) << 3) + h;
    const int n0 = bm & 1023;

    // staging bases: wave w stages rows w*16..w*16+16 (A and B-chunk)
    const u16* gA = qkws + (size_t)(bm + w * 16 + r8) * 1024 + qcol0 + (h << 6) + c8x;
    const u16* gB = wmb + (size_t)(w * 16 + r8) * 64 + c8x;

    auto stageB = [&](int buf, int c) {
        u16* lb = &Bs[buf][(w * 16) * 64];
        const u16* g = gB + (size_t)c * 128 * 64;
#pragma unroll
        for (int j = 0; j < 2; ++j)
            gload16(g + (size_t)j * 8 * 64, lb + j * 8 * 64);
    };

    // ---- prologue: A + bias/wv vectors + B chunk0 (all gload->LDS) ----
#pragma unroll
    for (int j = 0; j < 2; ++j)
        gload16(gA + (size_t)j * 8 * 1024, As + (w * 16 + j * 8) * 64);
    if (w < 4) {
        gloadf(biasv + w * 256 + lane * 4, biasL + w * 256);
        if constexpr (STG == 2)
            gloadf(wv2 + (bh << 10) + w * 256 + lane * 4, wv2L + w * 256);
    } else {
        gloadf(wv1 + (bh << 10) + (w - 4) * 256 + lane * 4, wv1L + (w - 4) * 256);
    }
    stageB(0, 0);
    __syncthreads();                                // drains all prologue loads

    // A fragments in registers for the whole kernel (rows wr*32..+32)
    short8 a[2][2];
#pragma unroll
    for (int nt = 0; nt < 2; ++nt)
#pragma unroll
        for (int kk = 0; kk < 2; ++kk)
            a[nt][kk] = *(const short8*)&As[(wr * 32 + nt * 16 + s) * 64 + (((kk * 4 + quad) ^ sx) << 3)];

    float rsf[2][4];
#pragma unroll
    for (int nt = 0; nt < 2; ++nt)
#pragma unroll
        for (int r = 0; r < 4; ++r) {
            if constexpr (STG == 2)
                rsf[nt][r] = wv1L[n0 + wr * 32 + nt * 16 + quad * 4 + r] * SCL2;
            else
                rsf[nt][r] = SCL2;
        }

    float z[2][4] = {}, wacc[2][4] = {};
    const int ct0 = mg * 4;                         // this wave's ct-half
    int cur = 0;

#pragma unroll 1
    for (int c = 0; c < 8; ++c) {
        const int nxt = (cur == 2) ? 0 : cur + 1;
        if (c < 7) {
            stageB(nxt, c + 1);                     // issue next-chunk loads
            asm volatile("s_waitcnt vmcnt(2)" ::: "memory");  // chunk c landed
        } else {
            asm volatile("s_waitcnt vmcnt(0)" ::: "memory");
        }
        __builtin_amdgcn_s_barrier();               // all waves' chunk c staged
        __builtin_amdgcn_sched_barrier(0);          // pin reads below barrier

        // bias / wv for this wave's ct-half -- pure LDS (no VMEM in loop!)
        float bmv[4], wvv[4];
#pragma unroll
        for (int i = 0; i < 4; ++i) {
            const int m = c * 128 + (ct0 + i) * 16 + s;
            bmv[i] = biasL[m] * SCL2;
            float wv = wv1L[m];
            if constexpr (STG == 2) wv *= wv2L[m];
            wvv[i] = wv;
        }

        const u16* Bb = Bs[cur];
#pragma unroll
        for (int i = 0; i < 4; ++i) {
            const int ct = ct0 + i;
            const short8 b0 = *(const short8*)&Bb[(ct * 16 + s) * 64 + ((quad ^ sx) << 3)];
            const short8 b1 = *(const short8*)&Bb[(ct * 16 + s) * 64 + (((4 + quad) ^ sx) << 3)];
#pragma unroll
            for (int nt = 0; nt < 2; ++nt) {
                f32x4 acc = (f32x4){0.f, 0.f, 0.f, 0.f};
                acc = MFMA16(a[nt][0], b0, acc);
                acc = MFMA16(a[nt][1], b1, acc);
#pragma unroll
                for (int r = 0; r < 4; ++r) {
                    const float e = __builtin_amdgcn_exp2f(rsf[nt][r] * acc[r] + bmv[i]);
                    z[nt][r] += e;
                    wacc[nt][r] += e * wvv[i];
                }
            }
        }
        cur = nxt;                                  // no trailing barrier (N=3)
    }

    // reduce over the 16 m-lanes; s==0 writes the wave's partial plane
#pragma unroll
    for (int nt = 0; nt < 2; ++nt)
#pragma unroll
        for (int r = 0; r < 4; ++r) {
            float Z = z[nt][r], W = wacc[nt][r];
            for (int off = 1; off < 16; off <<= 1) {
                Z += __shfl_xor(Z, off);
                W += __shfl_xor(W, off);
            }
            if (s == 0) {
                const int rowl = wr * 32 + nt * 16 + quad * 4 + r;
                zp[mg][rowl] = Z;
                wp[mg][rowl] = W;
            }
        }
    __syncthreads();
    if (t < 128) {
        const float Z = zp[0][t] + zp[1][t];
        const float W = wp[0][t] + wp[1][t];
        outg[(bh << 10) + n0 + t] = W / Z;
    }
}

// ---------------------------------------------------------------------------
extern "C" void kernel_launch(void* const* d_in, const int* in_sizes, int n_in,
                              void* d_out, int out_size, void* d_ws, size_t ws_size,
                              hipStream_t stream)
{
    const float* x     = (const float*)d_in[0];
    const float* w_qkv = (const float*)d_in[1];
    const float* b_qkv = (const float*)d_in[2];
    const float* wq    = (const float*)d_in[3];
    const float* bq    = (const float*)d_in[4];
    const float* wk    = (const float*)d_in[5];
    const float* bk    = (const float*)d_in[6];
    const float* w_out = (const float*)d_in[7];
    const float* b_out = (const float*)d_in[8];
    float* out = (float*)d_out;

    // ws: qs|ks|qg|kg (65536 f32) | bf16: wqkv|wout|wq|wk|x | qk ws bf16
    float* qs = (float*)d_ws;
    float* ks = qs + 65536;
    float* qg = ks + 65536;
    float* kg = qg + 65536;
    u16* wsb   = (u16*)(kg + 65536);
    u16* wqkvb = wsb;
    u16* woutb = wqkvb + 786432;
    u16* wqb   = woutb + 262144;
    u16* wkb   = wqb + 65536;
    u16* xb    = wkb + 65536;
    u16* qkws  = xb + 4194304;

    // 5,373,952 f32 -> bf16 (weights + x), 4 elems/thread
    conv_kernel<<<5248, 256, 0, stream>>>(w_qkv, w_out, wq, wk, x, wsb);
    // QK: qk = x @ w_qkv[0:1024]^T + b_qkv  (128x128 tile) + fused qs/ks
    gemm_k<MQK, 8><<<dim3(64, 8), 256, 0, stream>>>(
        xb, 512, 0, wqkvb, b_qkv, nullptr, nullptr, qkws, nullptr, qs, ks);
    // stage 1 -> qg
    stage_gemm<1><<<dim3(64, 8), 512, 0, stream>>>(
        qkws, 0, wqb, bq, qs, nullptr, qg);
    // stage 2 -> kg
    stage_gemm<2><<<dim3(64, 8), 512, 0, stream>>>(
        qkws, 512, wkb, bk, qg, ks, kg);
    // VU: U = (x @ w_qkv[1024:]^T + bv) * kg  (into k-half of qk ws)
    gemm_k<MVU, 4><<<dim3(64, 8), 256, 0, stream>>>(
        xb, 512, 0, wqkvb + (size_t)1024 * 512, b_qkv + 1024, kg, nullptr, qkws,
        nullptr, nullptr, nullptr);
    // OUT: out = U @ w_out^T + b_out + qo
    gemm_k<MOUT, 4><<<dim3(64, 8), 256, 0, stream>>>(
        qkws, 1024, 512, woutb, b_out, nullptr, qkws, nullptr, out, nullptr, nullptr);
}